// Round 2
// baseline (1418.135 us; speedup 1.0000x reference)
//
#include <hip/hip_runtime.h>
#include <hip/hip_bf16.h>
#include <cstdint>
#include <cstddef>

#define T_SEQ 2048
#define NH 16
#define DQK 192
#define DV 128

typedef __attribute__((ext_vector_type(8))) short short8;
typedef __attribute__((ext_vector_type(4))) float f32x4;

__device__ __forceinline__ void load_lds_16(const void* g, void* l) {
    __builtin_amdgcn_global_load_lds(
        (const __attribute__((address_space(1))) void*)g,
        (__attribute__((address_space(3))) void*)l, 16, 0, 0);
}

// ---------------------------------------------------------------------------
// fp32 -> bf16 convert with trailing zero pad (flat counts, multiples of 4)
__global__ void cvt_pad(const float* __restrict__ in, __hip_bfloat16* __restrict__ out,
                        long n_real, long n_pad) {
    long i = ((long)blockIdx.x * blockDim.x + threadIdx.x) * 4;
    const long stride = (long)gridDim.x * blockDim.x * 4;
    for (; i < n_pad; i += stride) {
        float v0 = 0.f, v1 = 0.f, v2 = 0.f, v3 = 0.f;
        if (i < n_real) {
            const float4 v = *(const float4*)(in + i);
            v0 = v.x; v1 = v.y; v2 = v.z; v3 = v.w;
        }
        out[i + 0] = __float2bfloat16(v0);
        out[i + 1] = __float2bfloat16(v1);
        out[i + 2] = __float2bfloat16(v2);
        out[i + 3] = __float2bfloat16(v3);
    }
}

// ---------------------------------------------------------------------------
__global__ __launch_bounds__(256) void rmsnorm_bf16(
    const float* __restrict__ x, const float* __restrict__ w,
    __hip_bfloat16* __restrict__ y, int D, int ldx) {
    const int row = blockIdx.x;
    const float* xr = x + (size_t)row * ldx;
    float ss = 0.f;
    for (int i = threadIdx.x; i < D; i += 256) { float v = xr[i]; ss += v * v; }
    for (int off = 32; off > 0; off >>= 1) ss += __shfl_down(ss, off);
    __shared__ float part[4];
    if ((threadIdx.x & 63) == 0) part[threadIdx.x >> 6] = ss;
    __syncthreads();
    const float tot = part[0] + part[1] + part[2] + part[3];
    const float rs = rsqrtf(tot / (float)D + 1e-6f);
    __hip_bfloat16* yr = y + (size_t)row * D;
    for (int i = threadIdx.x; i < D; i += 256)
        yr[i] = __float2bfloat16(xr[i] * rs * w[i]);
}

// ---------------------------------------------------------------------------
// C[M,N] = A[M,K](bf16) @ B[Npad,K](bf16)^T, 128x128 tile, BK=32.
// EPI: 0 = Cf fp32; 1 = Cf fp32 + Add; 2 = Cb bf16 = silu(acc); 3 = Cb *= acc (in place)
template<int EPI>
__global__ __launch_bounds__(256) void gemm_bt(
    const __hip_bfloat16* __restrict__ A, const __hip_bfloat16* __restrict__ B,
    float* __restrict__ Cf, __hip_bfloat16* __restrict__ Cb,
    const float* __restrict__ Add, int N, int K) {
    __shared__ __hip_bfloat16 As[128 * 32];
    __shared__ __hip_bfloat16 Bs[128 * 32];
    const int tid = threadIdx.x;
    const int wave = tid >> 6;
    const int lane = tid & 63;
    const int col = lane & 15;
    const int quad = lane >> 4;
    const long bm = (long)blockIdx.y * 128;
    const long bn = (long)blockIdx.x * 128;
    const int wm = (wave & 1) * 64;
    const int wn = (wave >> 1) * 64;

    const int f0 = tid * 8;
    const int r0 = f0 >> 5, c0 = f0 & 31;
    const int f1 = (256 + tid) * 8;
    const int r1 = f1 >> 5, c1 = f1 & 31;
    __hip_bfloat16* dstA0 = &As[wave * 512];
    __hip_bfloat16* dstA1 = &As[2048 + wave * 512];
    __hip_bfloat16* dstB0 = &Bs[wave * 512];
    __hip_bfloat16* dstB1 = &Bs[2048 + wave * 512];

    f32x4 acc[4][4];
    for (int i = 0; i < 4; i++)
        for (int j = 0; j < 4; j++) acc[i][j] = (f32x4){0.f, 0.f, 0.f, 0.f};

    for (int k0 = 0; k0 < K; k0 += 32) {
        __syncthreads();
        load_lds_16(A + (bm + r0) * (long)K + k0 + c0, dstA0);
        load_lds_16(A + (bm + r1) * (long)K + k0 + c1, dstA1);
        load_lds_16(B + (bn + r0) * (long)K + k0 + c0, dstB0);
        load_lds_16(B + (bn + r1) * (long)K + k0 + c1, dstB1);
        __syncthreads();
        short8 a[4], b[4];
        for (int i = 0; i < 4; i++)
            a[i] = *(const short8*)&As[(wm + 16 * i + col) * 32 + quad * 8];
        for (int j = 0; j < 4; j++)
            b[j] = *(const short8*)&Bs[(wn + 16 * j + col) * 32 + quad * 8];
        for (int i = 0; i < 4; i++)
            for (int j = 0; j < 4; j++)
                acc[i][j] = __builtin_amdgcn_mfma_f32_16x16x32_bf16(a[i], b[j], acc[i][j], 0, 0, 0);
    }

    for (int i = 0; i < 4; i++) {
        const long gm = bm + wm + 16 * i + quad * 4;
        for (int j = 0; j < 4; j++) {
            const long gn = bn + wn + 16 * j + col;
            if (gn < N) {
                for (int r = 0; r < 4; r++) {
                    const long idx = (gm + r) * (long)N + gn;
                    const float a0 = acc[i][j][r];
                    if (EPI == 0) {
                        Cf[idx] = a0;
                    } else if (EPI == 1) {
                        Cf[idx] = a0 + Add[idx];
                    } else if (EPI == 2) {
                        const float s = a0 / (1.f + __expf(-a0));
                        Cb[idx] = __float2bfloat16(s);
                    } else {
                        const float g = __bfloat162float(Cb[idx]);
                        Cb[idx] = __float2bfloat16(g * a0);
                    }
                }
            }
        }
    }
}

// ---------------------------------------------------------------------------
// RoPE + repack: q_full bf16 [H][T][192], k_full bf16 [H][T][192], Vt bf16 [H][128][T]
__global__ __launch_bounds__(256) void rope_pack(
    const float* __restrict__ q,    // [T][3072]
    const float* __restrict__ ckv,  // [T][576]
    const float* __restrict__ kv,   // [T][4096]
    const float* __restrict__ cosT, const float* __restrict__ sinT,
    __hip_bfloat16* __restrict__ qf, __hip_bfloat16* __restrict__ kf,
    __hip_bfloat16* __restrict__ vt) {
    const int t = blockIdx.x;
    const int tid = threadIdx.x;
    __shared__ float kemb[64];
    if (tid < 64) {
        const int j = tid;
        const int m = j & 31;
        const float c = cosT[t * 64 + j], s = sinT[t * 64 + j];
        const float x0 = ckv[(size_t)t * 576 + 512 + 2 * m];
        const float x1 = ckv[(size_t)t * 576 + 512 + 2 * m + 1];
        kemb[j] = (j >= 32) ? (x1 * c + x0 * s) : (x0 * c - x1 * s);
    }
    __syncthreads();
    for (int h = 0; h < NH; h++) {
        const size_t qrow = ((size_t)h * T_SEQ + t) * DQK;
        if (tid < 128) {
            qf[qrow + tid] = __float2bfloat16(q[(size_t)t * 3072 + h * DQK + tid]);
            kf[qrow + tid] = __float2bfloat16(kv[(size_t)t * 4096 + h * 256 + tid]);
            vt[((size_t)h * 128 + tid) * T_SEQ + t] =
                __float2bfloat16(kv[(size_t)t * 4096 + h * 256 + 128 + tid]);
        } else if (tid < 192) {
            const int j = tid - 128;
            const int m = j & 31;
            const float c = cosT[t * 64 + j], s = sinT[t * 64 + j];
            const float x0 = q[(size_t)t * 3072 + h * DQK + 128 + 2 * m];
            const float x1 = q[(size_t)t * 3072 + h * DQK + 128 + 2 * m + 1];
            const float v = (j >= 32) ? (x1 * c + x0 * s) : (x0 * c - x1 * s);
            qf[qrow + 128 + j] = __float2bfloat16(v);
            kf[qrow + 128 + j] = __float2bfloat16(kemb[j]);
        }
    }
}

// ---------------------------------------------------------------------------
// Flash attention (causal). Grid (T/64, H); 4 waves, each owns 16 q rows.
__global__ __launch_bounds__(256) void flash_attn(
    const __hip_bfloat16* __restrict__ Qf, const __hip_bfloat16* __restrict__ Kf,
    const __hip_bfloat16* __restrict__ Vt, __hip_bfloat16* __restrict__ Oout) {
    const int h = blockIdx.y;
    const int wave = threadIdx.x >> 6;
    const int lane = threadIdx.x & 63;
    const int col = lane & 15;
    const int quad = lane >> 4;
    const int q0 = blockIdx.x * 64 + wave * 16;
    __shared__ __hip_bfloat16 Plds[4][16 * 32];

    const __hip_bfloat16* Qh = Qf + (size_t)h * T_SEQ * DQK;
    const __hip_bfloat16* Kh = Kf + (size_t)h * T_SEQ * DQK;
    const __hip_bfloat16* Vh = Vt + (size_t)h * DV * T_SEQ;

    short8 qfr[6];
    for (int d = 0; d < 6; d++)
        qfr[d] = *(const short8*)&Qh[(size_t)(q0 + col) * DQK + d * 32 + quad * 8];

    float m_i[4], l_i[4];
    f32x4 o[8];
    for (int r = 0; r < 4; r++) { m_i[r] = -INFINITY; l_i[r] = 0.f; }
    for (int dt = 0; dt < 8; dt++) o[dt] = (f32x4){0.f, 0.f, 0.f, 0.f};

    const float scaling = 0.07216878364870323f; // 192^-0.5

    for (int kc = 0; kc < q0 + 16; kc += 32) {
        f32x4 s0 = {0.f, 0.f, 0.f, 0.f}, s1 = {0.f, 0.f, 0.f, 0.f};
        for (int d = 0; d < 6; d++) {
            short8 k0f = *(const short8*)&Kh[(size_t)(kc + col) * DQK + d * 32 + quad * 8];
            short8 k1f = *(const short8*)&Kh[(size_t)(kc + 16 + col) * DQK + d * 32 + quad * 8];
            s0 = __builtin_amdgcn_mfma_f32_16x16x32_bf16(qfr[d], k0f, s0, 0, 0, 0);
            s1 = __builtin_amdgcn_mfma_f32_16x16x32_bf16(qfr[d], k1f, s1, 0, 0, 0);
        }
        float p0[4], p1[4], mx[4], alpha[4], rsum[4];
        for (int r = 0; r < 4; r++) {
            const int row = q0 + quad * 4 + r;
            float v0 = s0[r] * scaling;
            float v1 = s1[r] * scaling;
            if (kc + col > row) v0 = -1e30f;
            if (kc + 16 + col > row) v1 = -1e30f;
            s0[r] = v0; s1[r] = v1;
            mx[r] = fmaxf(v0, v1);
        }
        for (int off = 1; off < 16; off <<= 1)
            for (int r = 0; r < 4; r++)
                mx[r] = fmaxf(mx[r], __shfl_xor(mx[r], off));
        for (int r = 0; r < 4; r++) {
            const float mnew = fmaxf(m_i[r], mx[r]);
            p0[r] = __expf(s0[r] - mnew);
            p1[r] = __expf(s1[r] - mnew);
            alpha[r] = __expf(m_i[r] - mnew);
            m_i[r] = mnew;
            rsum[r] = p0[r] + p1[r];
        }
        for (int off = 1; off < 16; off <<= 1)
            for (int r = 0; r < 4; r++)
                rsum[r] += __shfl_xor(rsum[r], off);
        for (int r = 0; r < 4; r++) l_i[r] = l_i[r] * alpha[r] + rsum[r];
        for (int dt = 0; dt < 8; dt++)
            for (int r = 0; r < 4; r++) o[dt][r] *= alpha[r];
        for (int r = 0; r < 4; r++) {
            Plds[wave][(quad * 4 + r) * 32 + col] = __float2bfloat16(p0[r]);
            Plds[wave][(quad * 4 + r) * 32 + 16 + col] = __float2bfloat16(p1[r]);
        }
        asm volatile("s_waitcnt lgkmcnt(0)" ::: "memory");
        short8 pa = *(const short8*)&Plds[wave][col * 32 + quad * 8];
        for (int dt = 0; dt < 8; dt++) {
            short8 bv = *(const short8*)&Vh[(size_t)(dt * 16 + col) * T_SEQ + kc + quad * 8];
            o[dt] = __builtin_amdgcn_mfma_f32_16x16x32_bf16(pa, bv, o[dt], 0, 0, 0);
        }
    }

    for (int r = 0; r < 4; r++) {
        const int row = q0 + quad * 4 + r;
        const float inv = 1.f / l_i[r];
        for (int dt = 0; dt < 8; dt++)
            Oout[(size_t)row * (NH * DV) + h * DV + dt * 16 + col] =
                __float2bfloat16(o[dt][r] * inv);
    }
}

// ---------------------------------------------------------------------------
__global__ void fill_f32(float* __restrict__ y, long n, float v) {
    long i = (long)blockIdx.x * blockDim.x + threadIdx.x;
    const long st = (long)gridDim.x * blockDim.x;
    for (; i < n; i += st) y[i] = v;
}

// ---------------------------------------------------------------------------
extern "C" void kernel_launch(void* const* d_in, const int* in_sizes, int n_in,
                              void* d_out, int out_size, void* d_ws, size_t ws_size,
                              hipStream_t stream) {
    const float* hidden   = (const float*)d_in[0];
    const float* cosT     = (const float*)d_in[1];
    const float* sinT     = (const float*)d_in[2];
    const float* ln_input = (const float*)d_in[3];
    const float* w_q_a    = (const float*)d_in[4];
    const float* ln_q_a   = (const float*)d_in[5];
    const float* w_q_b    = (const float*)d_in[6];
    const float* w_kv_a   = (const float*)d_in[7];
    const float* ln_kv_a  = (const float*)d_in[8];
    const float* w_kv_b   = (const float*)d_in[9];
    const float* w_o      = (const float*)d_in[10];
    const float* ln_post  = (const float*)d_in[11];
    const float* w_gate   = (const float*)d_in[12];
    const float* w_up     = (const float*)d_in[13];
    const float* w_down   = (const float*)d_in[14];
    float* out = (float*)d_out;

    char* ws = (char*)d_ws;
    size_t off = 0;
    auto alloc = [&](size_t bytes) -> char* {
        off = (off + 255) & ~(size_t)255;
        char* p = ws + off;
        off += bytes;
        return p;
    };

    // Arena regions with lifetime-based aliasing (peak ~157.5 MB)
    char* W_ = alloc(11008l * 2048 * 2);                 // weight scratch (reused x8)
    char* A_ = alloc(2048l * 3072 * 4);                  // h_b -> q_f -> attn_b -> h2_b
    char* B_ = alloc(2048l * 10944 * 2);                 // qa_f -> kv_f -> gate/act (bf16)
    char* C_ = alloc(2048l * 576 * 4);                   // ckv_f
    char* D_ = alloc(2048l * 2048 * 4);                  // {qan,ckvn} -> kf -> res_f
    char* E_ = alloc((16l * 2048 * 192 + 16l * 128 * 2048) * 2); // qf + vt

    if (off > ws_size) {
        fill_f32<<<2048, 256, 0, stream>>>(out, (long)out_size, -77777.0f);
        return;
    }

    auto* Wb     = (__hip_bfloat16*)W_;
    auto* h_b    = (__hip_bfloat16*)A_;
    auto* q_f    = (float*)A_;
    auto* attn_b = (__hip_bfloat16*)A_;
    auto* h2_b   = (__hip_bfloat16*)A_;
    auto* qa_f   = (float*)B_;
    auto* kv_f   = (float*)B_;
    auto* gate_b = (__hip_bfloat16*)B_;
    auto* ckv_f  = (float*)C_;
    auto* qan_b  = (__hip_bfloat16*)D_;
    auto* ckvn_b = (__hip_bfloat16*)(D_ + 2048l * 1536 * 2);
    auto* kf_b   = (__hip_bfloat16*)D_;
    auto* res_f  = (float*)D_;
    auto* qf_b   = (__hip_bfloat16*)E_;
    auto* vt_b   = (__hip_bfloat16*)(E_ + 16l * 2048 * 192 * 2);

    auto cvt = [&](const float* src, long n_real, long n_pad) {
        cvt_pad<<<2048, 256, 0, stream>>>(src, Wb, n_real, n_pad);
    };
    auto gemm = [&](int EPI, const __hip_bfloat16* A, float* Cf, __hip_bfloat16* Cb,
                    const float* Add, int N, int Npad, int K) {
        dim3 g(Npad / 128, 16);
        if (EPI == 0)      gemm_bt<0><<<g, 256, 0, stream>>>(A, Wb, Cf, Cb, Add, N, K);
        else if (EPI == 1) gemm_bt<1><<<g, 256, 0, stream>>>(A, Wb, Cf, Cb, Add, N, K);
        else if (EPI == 2) gemm_bt<2><<<g, 256, 0, stream>>>(A, Wb, Cf, Cb, Add, N, K);
        else               gemm_bt<3><<<g, 256, 0, stream>>>(A, Wb, Cf, Cb, Add, N, K);
    };

    // attention pipeline
    rmsnorm_bf16<<<2048, 256, 0, stream>>>(hidden, ln_input, h_b, 2048, 2048);
    cvt(w_q_a, 1536l * 2048, 1536l * 2048);
    gemm(0, h_b, qa_f, nullptr, nullptr, 1536, 1536, 2048);
    cvt(w_kv_a, 576l * 2048, 640l * 2048);
    gemm(0, h_b, ckv_f, nullptr, nullptr, 576, 640, 2048);
    rmsnorm_bf16<<<2048, 256, 0, stream>>>(qa_f, ln_q_a, qan_b, 1536, 1536);
    rmsnorm_bf16<<<2048, 256, 0, stream>>>(ckv_f, ln_kv_a, ckvn_b, 512, 576);
    cvt(w_q_b, 3072l * 1536, 3072l * 1536);
    gemm(0, qan_b, q_f, nullptr, nullptr, 3072, 3072, 1536);
    cvt(w_kv_b, 4096l * 512, 4096l * 512);
    gemm(0, ckvn_b, kv_f, nullptr, nullptr, 4096, 4096, 512);
    rope_pack<<<2048, 256, 0, stream>>>(q_f, ckv_f, kv_f, cosT, sinT, qf_b, kf_b, vt_b);
    flash_attn<<<dim3(32, 16), 256, 0, stream>>>(qf_b, kf_b, vt_b, attn_b);
    cvt(w_o, 2048l * 2048, 2048l * 2048);
    gemm(1, attn_b, res_f, nullptr, hidden, 2048, 2048, 2048);  // res = attn@wo^T + hidden

    // MLP
    rmsnorm_bf16<<<2048, 256, 0, stream>>>(res_f, ln_post, h2_b, 2048, 2048);
    cvt(w_gate, 10944l * 2048, 11008l * 2048);
    gemm(2, h2_b, nullptr, gate_b, nullptr, 10944, 11008, 2048); // gate = silu(h2@wg^T)
    cvt(w_up, 10944l * 2048, 11008l * 2048);
    gemm(3, h2_b, nullptr, gate_b, nullptr, 10944, 11008, 2048); // act = gate * (h2@wu^T)
    cvt(w_down, 2048l * 10944, 2048l * 10944);
    gemm(1, gate_b, out, nullptr, res_f, 2048, 2048, 10944);     // out = act@wd^T + res
}

// Round 3
// 1221.863 us; speedup vs baseline: 1.1606x; 1.1606x over previous
//
#include <hip/hip_runtime.h>
#include <hip/hip_bf16.h>
#include <cstdint>
#include <cstddef>

#define T_SEQ 2048
#define NH 16
#define DQK 192
#define DV 128

typedef __attribute__((ext_vector_type(8))) short short8;
typedef __attribute__((ext_vector_type(4))) float f32x4;

__device__ __forceinline__ void load_lds_16(const void* g, void* l) {
    __builtin_amdgcn_global_load_lds(
        (const __attribute__((address_space(1))) void*)g,
        (__attribute__((address_space(3))) void*)l, 16, 0, 0);
}

// ---------------------------------------------------------------------------
__global__ void cvt_pad(const float* __restrict__ in, __hip_bfloat16* __restrict__ out,
                        long n_real, long n_pad) {
    long i = ((long)blockIdx.x * blockDim.x + threadIdx.x) * 4;
    const long stride = (long)gridDim.x * blockDim.x * 4;
    for (; i < n_pad; i += stride) {
        float v0 = 0.f, v1 = 0.f, v2 = 0.f, v3 = 0.f;
        if (i < n_real) {
            const float4 v = *(const float4*)(in + i);
            v0 = v.x; v1 = v.y; v2 = v.z; v3 = v.w;
        }
        out[i + 0] = __float2bfloat16(v0);
        out[i + 1] = __float2bfloat16(v1);
        out[i + 2] = __float2bfloat16(v2);
        out[i + 3] = __float2bfloat16(v3);
    }
}

// ---------------------------------------------------------------------------
__global__ __launch_bounds__(256) void rmsnorm_bf16(
    const float* __restrict__ x, const float* __restrict__ w,
    __hip_bfloat16* __restrict__ y, int D, int ldx) {
    const int row = blockIdx.x;
    const float* xr = x + (size_t)row * ldx;
    float ss = 0.f;
    for (int i = threadIdx.x; i < D; i += 256) { float v = xr[i]; ss += v * v; }
    for (int off = 32; off > 0; off >>= 1) ss += __shfl_down(ss, off);
    __shared__ float part[4];
    if ((threadIdx.x & 63) == 0) part[threadIdx.x >> 6] = ss;
    __syncthreads();
    const float tot = part[0] + part[1] + part[2] + part[3];
    const float rs = rsqrtf(tot / (float)D + 1e-6f);
    __hip_bfloat16* yr = y + (size_t)row * D;
    for (int i = threadIdx.x; i < D; i += 256)
        yr[i] = __float2bfloat16(xr[i] * rs * w[i]);
}

// ---------------------------------------------------------------------------
// C[M,N] = A[M,K](bf16) @ B[Npad,K](bf16)^T, 128x128 tile, BK=32.
// EPI: 0 = Cf fp32; 1 = Cf fp32 + Add; 2 = Cb bf16 = silu(acc); 3 = Cb *= acc
template<int EPI>
__global__ __launch_bounds__(256) void gemm_bt(
    const __hip_bfloat16* __restrict__ A, const __hip_bfloat16* __restrict__ B,
    float* __restrict__ Cf, __hip_bfloat16* __restrict__ Cb,
    const float* __restrict__ Add, int N, int K) {
    __shared__ __hip_bfloat16 As[128 * 32];
    __shared__ __hip_bfloat16 Bs[128 * 32];
    const int tid = threadIdx.x;
    const int wave = tid >> 6;
    const int lane = tid & 63;
    const int col = lane & 15;
    const int quad = lane >> 4;
    const long bm = (long)blockIdx.y * 128;
    const long bn = (long)blockIdx.x * 128;
    const int wm = (wave & 1) * 64;
    const int wn = (wave >> 1) * 64;

    const int f0 = tid * 8;
    const int r0 = f0 >> 5, c0 = f0 & 31;
    const int f1 = (256 + tid) * 8;
    const int r1 = f1 >> 5, c1 = f1 & 31;
    __hip_bfloat16* dstA0 = &As[wave * 512];
    __hip_bfloat16* dstA1 = &As[2048 + wave * 512];
    __hip_bfloat16* dstB0 = &Bs[wave * 512];
    __hip_bfloat16* dstB1 = &Bs[2048 + wave * 512];

    f32x4 acc[4][4];
    for (int i = 0; i < 4; i++)
        for (int j = 0; j < 4; j++) acc[i][j] = (f32x4){0.f, 0.f, 0.f, 0.f};

    for (int k0 = 0; k0 < K; k0 += 32) {
        __syncthreads();
        load_lds_16(A + (bm + r0) * (long)K + k0 + c0, dstA0);
        load_lds_16(A + (bm + r1) * (long)K + k0 + c1, dstA1);
        load_lds_16(B + (bn + r0) * (long)K + k0 + c0, dstB0);
        load_lds_16(B + (bn + r1) * (long)K + k0 + c1, dstB1);
        __syncthreads();
        short8 a[4], b[4];
        for (int i = 0; i < 4; i++)
            a[i] = *(const short8*)&As[(wm + 16 * i + col) * 32 + quad * 8];
        for (int j = 0; j < 4; j++)
            b[j] = *(const short8*)&Bs[(wn + 16 * j + col) * 32 + quad * 8];
        for (int i = 0; i < 4; i++)
            for (int j = 0; j < 4; j++)
                acc[i][j] = __builtin_amdgcn_mfma_f32_16x16x32_bf16(a[i], b[j], acc[i][j], 0, 0, 0);
    }

    for (int i = 0; i < 4; i++) {
        const long gm = bm + wm + 16 * i + quad * 4;
        for (int j = 0; j < 4; j++) {
            const long gn = bn + wn + 16 * j + col;
            if (gn < N) {
                for (int r = 0; r < 4; r++) {
                    const long idx = (gm + r) * (long)N + gn;
                    const float a0 = acc[i][j][r];
                    if (EPI == 0) {
                        Cf[idx] = a0;
                    } else if (EPI == 1) {
                        Cf[idx] = a0 + Add[idx];
                    } else if (EPI == 2) {
                        const float s = a0 / (1.f + __expf(-a0));
                        Cb[idx] = __float2bfloat16(s);
                    } else {
                        const float g = __bfloat162float(Cb[idx]);
                        Cb[idx] = __float2bfloat16(g * a0);
                    }
                }
            }
        }
    }
}

// ---------------------------------------------------------------------------
// RoPE + repack: q_full bf16 [H][T][192], k_full bf16 [H][T][192], Vt bf16 [H][128][T]
__global__ __launch_bounds__(256) void rope_pack(
    const float* __restrict__ q, const float* __restrict__ ckv,
    const float* __restrict__ kv,
    const float* __restrict__ cosT, const float* __restrict__ sinT,
    __hip_bfloat16* __restrict__ qf, __hip_bfloat16* __restrict__ kf,
    __hip_bfloat16* __restrict__ vt) {
    const int t = blockIdx.x;
    const int tid = threadIdx.x;
    __shared__ float kemb[64];
    if (tid < 64) {
        const int j = tid;
        const int m = j & 31;
        const float c = cosT[t * 64 + j], s = sinT[t * 64 + j];
        const float x0 = ckv[(size_t)t * 576 + 512 + 2 * m];
        const float x1 = ckv[(size_t)t * 576 + 512 + 2 * m + 1];
        kemb[j] = (j >= 32) ? (x1 * c + x0 * s) : (x0 * c - x1 * s);
    }
    __syncthreads();
    for (int h = 0; h < NH; h++) {
        const size_t qrow = ((size_t)h * T_SEQ + t) * DQK;
        if (tid < 128) {
            qf[qrow + tid] = __float2bfloat16(q[(size_t)t * 3072 + h * DQK + tid]);
            kf[qrow + tid] = __float2bfloat16(kv[(size_t)t * 4096 + h * 256 + tid]);
            vt[((size_t)h * 128 + tid) * T_SEQ + t] =
                __float2bfloat16(kv[(size_t)t * 4096 + h * 256 + 128 + tid]);
        } else if (tid < 192) {
            const int j = tid - 128;
            const int m = j & 31;
            const float c = cosT[t * 64 + j], s = sinT[t * 64 + j];
            const float x0 = q[(size_t)t * 3072 + h * DQK + 128 + 2 * m];
            const float x1 = q[(size_t)t * 3072 + h * DQK + 128 + 2 * m + 1];
            const float v = (j >= 32) ? (x1 * c + x0 * s) : (x0 * c - x1 * s);
            qf[qrow + 128 + j] = __float2bfloat16(v);
            kf[qrow + 128 + j] = __float2bfloat16(kemb[j]);
        }
    }
}

// ---------------------------------------------------------------------------
// Flash attention v2 (causal). Grid (32, 16): bx -> q-tile via balance remap,
// by = head. 4 waves share each kc-tile (64-wide) staged in LDS; wave w owns
// q rows [qtile*64 + w*16, +16).
// LDS K rows padded to 208 elem (416 B) and V rows to 80 elem (160 B): 4-way
// bank conflicts (1.58x) instead of 16-way. Pad mapping applied on the
// global-source side since global_load_lds dest is lane-contiguous.
#define KROW 208
#define VROW 80
#define PROW 72

__global__ __launch_bounds__(256) void flash_attn(
    const __hip_bfloat16* __restrict__ Qf, const __hip_bfloat16* __restrict__ Kf,
    const __hip_bfloat16* __restrict__ Vt, __hip_bfloat16* __restrict__ Oout) {
    const int h = blockIdx.y;
    const int qt = (h < 8) ? blockIdx.x : (31 - blockIdx.x); // causal load balance
    const int tid = threadIdx.x;
    const int wave = tid >> 6;
    const int lane = tid & 63;
    const int col = lane & 15;
    const int quad = lane >> 4;
    const int q0b = qt * 64;
    const int q0w = q0b + wave * 16;

    __shared__ __hip_bfloat16 Ks[1792 * 8];       // 64 x 208 (+ slack) = 28672 B
    __shared__ __hip_bfloat16 Vs[128 * VROW];     // 128 x 80 = 20480 B
    __shared__ __hip_bfloat16 Plds[4][16 * PROW]; // 9216 B

    const __hip_bfloat16* Qh = Qf + (size_t)h * T_SEQ * DQK;
    const __hip_bfloat16* Kh = Kf + (size_t)h * T_SEQ * DQK;
    const __hip_bfloat16* Vh = Vt + (size_t)h * DV * T_SEQ;

    short8 qfr[6];
    for (int d = 0; d < 6; d++)
        qfr[d] = *(const short8*)&Qh[(size_t)(q0w + col) * DQK + d * 32 + quad * 8];

    float m_i[4], l_i[4];
    f32x4 o[8];
    for (int r = 0; r < 4; r++) { m_i[r] = -INFINITY; l_i[r] = 0.f; }
    for (int dt = 0; dt < 8; dt++) o[dt] = (f32x4){0.f, 0.f, 0.f, 0.f};

    const float scaling = 0.07216878364870323f; // 192^-0.5
    const int kc_end = q0b + 64;

    for (int kc = 0; kc < kc_end; kc += 64) {
        __syncthreads();
        // stage K tile: 64 rows x 384 real bytes into 416 B-padded rows (7 KB-issues/wave)
        #pragma unroll
        for (int it = 0; it < 7; it++) {
            const int L = (it * 256 + tid) * 16;
            const int row = L / 416;
            const int c16 = (L % 416) / 16;
            const __hip_bfloat16* src = (row < 64 && c16 < 24)
                ? Kh + (size_t)(kc + row) * DQK + c16 * 8 : Kh;
            load_lds_16(src, (char*)Ks + it * 4096 + wave * 1024);
        }
        // stage V tile: 128 rows x 128 real bytes into 160 B-padded rows (5 issues/wave)
        #pragma unroll
        for (int it = 0; it < 5; it++) {
            const int L = (it * 256 + tid) * 16;
            const int row = L / 160;
            const int c16 = (L % 160) / 16;
            const __hip_bfloat16* src = (c16 < 8)
                ? Vh + (size_t)row * T_SEQ + kc + c16 * 8 : Vh;
            load_lds_16(src, (char*)Vs + it * 4096 + wave * 1024);
        }
        __syncthreads();

        // S = Q K^T for 4 16-col fragments
        f32x4 s[4];
        for (int f = 0; f < 4; f++) s[f] = (f32x4){0.f, 0.f, 0.f, 0.f};
        for (int d = 0; d < 6; d++)
            for (int f = 0; f < 4; f++) {
                short8 b = *(const short8*)&Ks[(f * 16 + col) * KROW + d * 32 + quad * 8];
                s[f] = __builtin_amdgcn_mfma_f32_16x16x32_bf16(qfr[d], b, s[f], 0, 0, 0);
            }

        // mask + online softmax
        float mx[4];
        for (int r = 0; r < 4; r++) mx[r] = -1e30f;
        for (int f = 0; f < 4; f++)
            for (int r = 0; r < 4; r++) {
                const int rowq = q0w + quad * 4 + r;
                const int kcol = kc + f * 16 + col;
                float v = s[f][r] * scaling;
                if (kcol > rowq) v = -1e30f;
                s[f][r] = v;
                mx[r] = fmaxf(mx[r], v);
            }
        for (int off = 1; off < 16; off <<= 1)
            for (int r = 0; r < 4; r++)
                mx[r] = fmaxf(mx[r], __shfl_xor(mx[r], off));
        float alpha[4], rsum[4];
        for (int r = 0; r < 4; r++) {
            const float mnew = fmaxf(m_i[r], mx[r]);
            alpha[r] = __expf(m_i[r] - mnew);
            m_i[r] = mnew;
            rsum[r] = 0.f;
        }
        float p[4][4];
        for (int f = 0; f < 4; f++)
            for (int r = 0; r < 4; r++) {
                p[f][r] = __expf(s[f][r] - m_i[r]);
                rsum[r] += p[f][r];
            }
        for (int off = 1; off < 16; off <<= 1)
            for (int r = 0; r < 4; r++)
                rsum[r] += __shfl_xor(rsum[r], off);
        for (int r = 0; r < 4; r++) l_i[r] = l_i[r] * alpha[r] + rsum[r];
        for (int dt = 0; dt < 8; dt++)
            for (int r = 0; r < 4; r++) o[dt][r] *= alpha[r];

        // P (C-layout) -> LDS -> A-layout
        for (int f = 0; f < 4; f++)
            for (int r = 0; r < 4; r++)
                Plds[wave][(quad * 4 + r) * PROW + f * 16 + col] = __float2bfloat16(p[f][r]);
        asm volatile("s_waitcnt lgkmcnt(0)" ::: "memory");
        short8 pa[2];
        for (int c = 0; c < 2; c++)
            pa[c] = *(const short8*)&Plds[wave][col * PROW + c * 32 + quad * 8];

        // O += P V
        for (int dt = 0; dt < 8; dt++)
            for (int c = 0; c < 2; c++) {
                short8 bv = *(const short8*)&Vs[(dt * 16 + col) * VROW + c * 32 + quad * 8];
                o[dt] = __builtin_amdgcn_mfma_f32_16x16x32_bf16(pa[c], bv, o[dt], 0, 0, 0);
            }
    }

    for (int r = 0; r < 4; r++) {
        const int row = q0w + quad * 4 + r;
        const float inv = 1.f / l_i[r];
        for (int dt = 0; dt < 8; dt++)
            Oout[(size_t)row * (NH * DV) + h * DV + dt * 16 + col] =
                __float2bfloat16(o[dt][r] * inv);
    }
}

// ---------------------------------------------------------------------------
__global__ void fill_f32(float* __restrict__ y, long n, float v) {
    long i = (long)blockIdx.x * blockDim.x + threadIdx.x;
    const long st = (long)gridDim.x * blockDim.x;
    for (; i < n; i += st) y[i] = v;
}

// ---------------------------------------------------------------------------
extern "C" void kernel_launch(void* const* d_in, const int* in_sizes, int n_in,
                              void* d_out, int out_size, void* d_ws, size_t ws_size,
                              hipStream_t stream) {
    const float* hidden   = (const float*)d_in[0];
    const float* cosT     = (const float*)d_in[1];
    const float* sinT     = (const float*)d_in[2];
    const float* ln_input = (const float*)d_in[3];
    const float* w_q_a    = (const float*)d_in[4];
    const float* ln_q_a   = (const float*)d_in[5];
    const float* w_q_b    = (const float*)d_in[6];
    const float* w_kv_a   = (const float*)d_in[7];
    const float* ln_kv_a  = (const float*)d_in[8];
    const float* w_kv_b   = (const float*)d_in[9];
    const float* w_o      = (const float*)d_in[10];
    const float* ln_post  = (const float*)d_in[11];
    const float* w_gate   = (const float*)d_in[12];
    const float* w_up     = (const float*)d_in[13];
    const float* w_down   = (const float*)d_in[14];
    float* out = (float*)d_out;

    char* ws = (char*)d_ws;
    size_t off = 0;
    auto alloc = [&](size_t bytes) -> char* {
        off = (off + 255) & ~(size_t)255;
        char* p = ws + off;
        off += bytes;
        return p;
    };

    char* W_ = alloc(11008l * 2048 * 2);
    char* A_ = alloc(2048l * 3072 * 4);
    char* B_ = alloc(2048l * 10944 * 2);
    char* C_ = alloc(2048l * 576 * 4);
    char* D_ = alloc(2048l * 2048 * 4);
    char* E_ = alloc((16l * 2048 * 192 + 16l * 128 * 2048) * 2);

    if (off > ws_size) {
        fill_f32<<<2048, 256, 0, stream>>>(out, (long)out_size, -77777.0f);
        return;
    }

    auto* Wb     = (__hip_bfloat16*)W_;
    auto* h_b    = (__hip_bfloat16*)A_;
    auto* q_f    = (float*)A_;
    auto* attn_b = (__hip_bfloat16*)A_;
    auto* h2_b   = (__hip_bfloat16*)A_;
    auto* qa_f   = (float*)B_;
    auto* kv_f   = (float*)B_;
    auto* gate_b = (__hip_bfloat16*)B_;
    auto* ckv_f  = (float*)C_;
    auto* qan_b  = (__hip_bfloat16*)D_;
    auto* ckvn_b = (__hip_bfloat16*)(D_ + 2048l * 1536 * 2);
    auto* kf_b   = (__hip_bfloat16*)D_;
    auto* res_f  = (float*)D_;
    auto* qf_b   = (__hip_bfloat16*)E_;
    auto* vt_b   = (__hip_bfloat16*)(E_ + 16l * 2048 * 192 * 2);

    auto cvt = [&](const float* src, long n_real, long n_pad) {
        cvt_pad<<<2048, 256, 0, stream>>>(src, Wb, n_real, n_pad);
    };
    auto gemm = [&](int EPI, const __hip_bfloat16* A, float* Cf, __hip_bfloat16* Cb,
                    const float* Add, int N, int Npad, int K) {
        dim3 g(Npad / 128, 16);
        if (EPI == 0)      gemm_bt<0><<<g, 256, 0, stream>>>(A, Wb, Cf, Cb, Add, N, K);
        else if (EPI == 1) gemm_bt<1><<<g, 256, 0, stream>>>(A, Wb, Cf, Cb, Add, N, K);
        else if (EPI == 2) gemm_bt<2><<<g, 256, 0, stream>>>(A, Wb, Cf, Cb, Add, N, K);
        else               gemm_bt<3><<<g, 256, 0, stream>>>(A, Wb, Cf, Cb, Add, N, K);
    };

    // attention pipeline
    rmsnorm_bf16<<<2048, 256, 0, stream>>>(hidden, ln_input, h_b, 2048, 2048);
    cvt(w_q_a, 1536l * 2048, 1536l * 2048);
    gemm(0, h_b, qa_f, nullptr, nullptr, 1536, 1536, 2048);
    cvt(w_kv_a, 576l * 2048, 640l * 2048);
    gemm(0, h_b, ckv_f, nullptr, nullptr, 576, 640, 2048);
    rmsnorm_bf16<<<2048, 256, 0, stream>>>(qa_f, ln_q_a, qan_b, 1536, 1536);
    rmsnorm_bf16<<<2048, 256, 0, stream>>>(ckv_f, ln_kv_a, ckvn_b, 512, 576);
    cvt(w_q_b, 3072l * 1536, 3072l * 1536);
    gemm(0, qan_b, q_f, nullptr, nullptr, 3072, 3072, 1536);
    cvt(w_kv_b, 4096l * 512, 4096l * 512);
    gemm(0, ckvn_b, kv_f, nullptr, nullptr, 4096, 4096, 512);
    rope_pack<<<2048, 256, 0, stream>>>(q_f, ckv_f, kv_f, cosT, sinT, qf_b, kf_b, vt_b);
    flash_attn<<<dim3(32, 16), 256, 0, stream>>>(qf_b, kf_b, vt_b, attn_b);
    cvt(w_o, 2048l * 2048, 2048l * 2048);
    gemm(1, attn_b, res_f, nullptr, hidden, 2048, 2048, 2048);

    // MLP
    rmsnorm_bf16<<<2048, 256, 0, stream>>>(res_f, ln_post, h2_b, 2048, 2048);
    cvt(w_gate, 10944l * 2048, 11008l * 2048);
    gemm(2, h2_b, nullptr, gate_b, nullptr, 10944, 11008, 2048);
    cvt(w_up, 10944l * 2048, 11008l * 2048);
    gemm(3, h2_b, nullptr, gate_b, nullptr, 10944, 11008, 2048);
    cvt(w_down, 2048l * 10944, 2048l * 10944);
    gemm(1, gate_b, out, nullptr, res_f, 2048, 2048, 10944);
}